// Round 5
// baseline (207.715 us; speedup 1.0000x reference)
//
#include <hip/hip_runtime.h>
#include <hip/hip_bf16.h>

#define S_LEN 2048
#define EMB   1024
#define NH    16
#define HD    64
#define BATCH 2
#define MROWS (BATCH * S_LEN)   // 4096

typedef __attribute__((ext_vector_type(8))) short short8;    // 8 bf16 = 4 VGPR
typedef __attribute__((ext_vector_type(4))) float float4v;   // 4 fp32
typedef __attribute__((ext_vector_type(16))) float f32x16;   // 16 fp32 (32x32 acc)
typedef __attribute__((ext_vector_type(2))) unsigned int uint2v;

#define MFMA16(a, b, c) __builtin_amdgcn_mfma_f32_16x16x32_bf16((a), (b), (c), 0, 0, 0)
#define MFMA32(a, b, c) __builtin_amdgcn_mfma_f32_32x32x16_bf16((a), (b), (c), 0, 0, 0)

typedef unsigned short u16;
typedef unsigned int   u32;

__device__ __forceinline__ u16 f2bf(float f) {
    union { float f; u32 u; } v; v.f = f;
    u32 u = v.u;
    return (u16)((u + 0x7fffu + ((u >> 16) & 1u)) >> 16);  // RNE
}

// packed fp32x2 -> bf16x2 (HW RNE on gfx950; fallback manual)
#if __has_builtin(__builtin_amdgcn_cvt_pk_bf16_f32)
typedef __attribute__((ext_vector_type(2))) __bf16 bfx2;
__device__ __forceinline__ u32 pkbf(float a, float b) {
    union { bfx2 v; u32 u; } c;
    c.v = __builtin_amdgcn_cvt_pk_bf16_f32(a, b);
    return c.u;
}
#else
__device__ __forceinline__ u32 pkbf(float a, float b) {
    return (u32)f2bf(a) | ((u32)f2bf(b) << 16);
}
#endif

#if __has_builtin(__builtin_amdgcn_exp2f)
#define EXP2(x) __builtin_amdgcn_exp2f(x)
#else
#define EXP2(x) exp2f(x)
#endif

// half-wave (lane ^ 32) pair exchange:
//   X = r0: lanes<32 keep a, lanes>=32 get b[lane-32]
//   Y = r1: lanes<32 get a[lane+32], lanes>=32 keep b
#if __has_builtin(__builtin_amdgcn_permlane32_swap)
__device__ __forceinline__ void half_swap(u32 a, u32 b, u32& x, u32& y) {
    uint2v r = __builtin_amdgcn_permlane32_swap(a, b, false, false);
    x = r[0]; y = r[1];
}
#else
__device__ __forceinline__ void half_swap(u32 a, u32 b, u32& x, u32& y) {
    int addr = ((threadIdx.x ^ 32) & 63) << 2;
    u32 asw = (u32)__builtin_amdgcn_ds_bpermute(addr, (int)a);
    u32 bsw = (u32)__builtin_amdgcn_ds_bpermute(addr, (int)b);
    bool hi = (threadIdx.x & 32) != 0;
    x = hi ? bsw : a;
    y = hi ? b : asw;
}
#endif

// async 16B global->LDS (lds dest = wave-uniform base + lane*16)
typedef __attribute__((address_space(3))) unsigned char lds_u8;
typedef __attribute__((address_space(1))) const unsigned char glb_u8;
__device__ __forceinline__ void async_copy16(const void* g, void* l) {
    __builtin_amdgcn_global_load_lds((glb_u8*)g, (lds_u8*)l, 16, 0, 0);
}

// ---------------------------------------------------------------------------
// K0: fused prologue. z=0..3: convert+transpose weight z (Wq pre-scaled by
// 0.125*log2e so QK scores exit the MFMA in exp2 domain). z=4..7: x -> bf16.
// ---------------------------------------------------------------------------
__global__ __launch_bounds__(256) void prep_kernel(
    const float* __restrict__ x,
    const float* __restrict__ W0, const float* __restrict__ W1,
    const float* __restrict__ W2, const float* __restrict__ W3,
    u16* __restrict__ xb, u16* __restrict__ Wt) {
    const int z = blockIdx.z;
    const int tid = threadIdx.x;
    if (z >= 4) {
        int i = ((((z - 4) * 1024) + blockIdx.y * 32 + blockIdx.x) * 256 + tid) * 4;
        float4 f = *(const float4*)(x + i);
        uint2 o; o.x = pkbf(f.x, f.y); o.y = pkbf(f.z, f.w);
        *(uint2*)(xb + i) = o;
        return;
    }
    const float* W = (z == 0) ? W0 : (z == 1) ? W1 : (z == 2) ? W2 : W3;
    u16* dst = Wt + (size_t)z * EMB * EMB;
    const float sc = (z == 0) ? 0.18033688011112042f : 1.0f;
    __shared__ float tile[32][33];
    int c0 = blockIdx.x * 32, r0 = blockIdx.y * 32;
    int tx = tid & 31, ty = tid >> 5;
#pragma unroll
    for (int i = 0; i < 4; ++i)
        tile[ty + 8 * i][tx] = W[(size_t)(r0 + ty + 8 * i) * EMB + c0 + tx];
    __syncthreads();
#pragma unroll
    for (int i = 0; i < 4; ++i)
        dst[(size_t)(c0 + ty + 8 * i) * EMB + r0 + tx] = f2bf(tile[tx][ty + 8 * i] * sc);
}

// ---------------------------------------------------------------------------
// GEMM core (128x128): BK=32, depth-1 LDS double-buffer, xor swizzle
// s(row)=(row>>1)&3 (2-way on banks = free). Prefetch before MFMAs.
// ---------------------------------------------------------------------------
#define GEMM_STEP(B, KN)                                                                       \
    {                                                                                           \
        short8 a[4], b[4];                                                                      \
        _Pragma("unroll")                                                                       \
        for (int i = 0; i < 4; ++i) a[i] = *(const short8*)&As[B][wm * 64 + i * 16 + l15][ca];  \
        _Pragma("unroll")                                                                       \
        for (int j = 0; j < 4; ++j) b[j] = *(const short8*)&Bs[B][wn * 64 + j * 16 + l15][ca];  \
        if ((KN) < EMB) {                                                                       \
            for (int wl = wid; wl < 8; wl += 4) {                                               \
                async_copy16(&Ag[(size_t)(m0 + wl * 16 + rr) * EMB + (KN) + cc], &As[B ^ 1][wl * 16][0]); \
                async_copy16(&Bg[(size_t)(n0 + wl * 16 + rr) * EMB + (KN) + cc], &Bs[B ^ 1][wl * 16][0]); \
            }                                                                                   \
        }                                                                                       \
        _Pragma("unroll")                                                                       \
        for (int i = 0; i < 4; ++i)                                                             \
            _Pragma("unroll")                                                                   \
            for (int j = 0; j < 4; ++j)                                                         \
                acc[i][j] = MFMA16(a[i], b[j], acc[i][j]);                                      \
        __syncthreads();                                                                        \
    }

#define GEMM_CORE(A_, B_)                                                                      \
    const int tid = threadIdx.x;                                                                \
    const int lane = tid & 63, wid = tid >> 6;                                                  \
    const int wm = wid >> 1, wn = wid & 1;                                                      \
    const int l15 = lane & 15, lq = lane >> 4;                                                  \
    const int m0 = blockIdx.y * 128, n0 = blockIdx.x * 128;                                     \
    const u16* Ag = (A_);                                                                       \
    const u16* Bg = (B_);                                                                       \
    __shared__ u16 As[2][128][32];                                                              \
    __shared__ u16 Bs[2][128][32];                                                              \
    float4v acc[4][4] = {};                                                                     \
    const int rr = lane >> 2;                                                                   \
    const int cc = ((lane & 3) ^ ((rr >> 1) & 3)) * 8;                                          \
    const int ca = (lq ^ ((l15 >> 1) & 3)) * 8;                                                 \
    for (int wl = wid; wl < 8; wl += 4) {                                                       \
        async_copy16(&Ag[(size_t)(m0 + wl * 16 + rr) * EMB + cc], &As[0][wl * 16][0]);          \
        async_copy16(&Bg[(size_t)(n0 + wl * 16 + rr) * EMB + cc], &Bs[0][wl * 16][0]);          \
    }                                                                                           \
    __syncthreads();                                                                            \
    for (int k0 = 0; k0 < EMB; k0 += 64) {                                                      \
        GEMM_STEP(0, k0 + 32)                                                                   \
        GEMM_STEP(1, k0 + 64)                                                                   \
    }

// K2: fused 3-projection GEMM: z=0 Q[B,H,S,D], z=1 K[B,H,S,D], z=2 V^T[B,H,D,S]
__global__ __launch_bounds__(256) void gemm_proj_kernel(
    const u16* __restrict__ A, const u16* __restrict__ WtAll,
    u16* __restrict__ Qb, u16* __restrict__ Kb, u16* __restrict__ Vtb) {
    const int z = blockIdx.z;
    const u16* Wt = WtAll + (size_t)z * EMB * EMB;
    GEMM_CORE(A, Wt)
#pragma unroll
    for (int i = 0; i < 4; ++i)
#pragma unroll
        for (int j = 0; j < 4; ++j) {
            int mb = m0 + wm * 64 + i * 16 + lq * 4;      // 4 consecutive m
            int n  = n0 + wn * 64 + j * 16 + l15;
            int b_ = mb >> 11, s = mb & 2047;
            int h = n >> 6, d = n & 63;
            if (z == 2) {
                uint2 pv;
                pv.x = pkbf(acc[i][j][0], acc[i][j][1]);
                pv.y = pkbf(acc[i][j][2], acc[i][j][3]);
                *(uint2*)&Vtb[(((size_t)(b_ * NH + h) * HD + d) * S_LEN) + s] = pv;
            } else {
                u16* dst = (z == 1) ? Kb : Qb;
#pragma unroll
                for (int r = 0; r < 4; ++r)
                    dst[(((size_t)(b_ * NH + h) * S_LEN + s + r) * HD) + d] = f2bf(acc[i][j][r]);
            }
        }
}

// ---------------------------------------------------------------------------
// K4: output GEMM -> fp32. 128m x 64n tiles: grid (16,32) = 512 blocks.
// ---------------------------------------------------------------------------
__global__ __launch_bounds__(256) void gemm_out_kernel(
    const u16* __restrict__ A, const u16* __restrict__ Wt, float* __restrict__ out) {
    const int tid = threadIdx.x;
    const int lane = tid & 63, wid = tid >> 6;
    const int wm = wid >> 1, wn = wid & 1;
    const int l15 = lane & 15, lq = lane >> 4;
    const int m0 = blockIdx.y * 128, n0 = blockIdx.x * 64;
    __shared__ u16 As[2][128][32];
    __shared__ u16 Bs[2][64][32];
    float4v acc[4][2] = {};
    const int rr = lane >> 2;
    const int cc = ((lane & 3) ^ ((rr >> 1) & 3)) * 8;
    const int ca = (lq ^ ((l15 >> 1) & 3)) * 8;

#define GO_STAGE(B, KN)                                                                        \
    {                                                                                           \
        for (int wl = wid; wl < 8; wl += 4)                                                     \
            async_copy16(&A[(size_t)(m0 + wl * 16 + rr) * EMB + (KN) + cc], &As[B][wl * 16][0]);\
        async_copy16(&Wt[(size_t)(n0 + wid * 16 + rr) * EMB + (KN) + cc], &Bs[B][wid * 16][0]); \
    }
#define GO_STEP(B, KN)                                                                         \
    {                                                                                           \
        short8 a[4], b[2];                                                                      \
        _Pragma("unroll")                                                                       \
        for (int i = 0; i < 4; ++i) a[i] = *(const short8*)&As[B][wm * 64 + i * 16 + l15][ca];  \
        _Pragma("unroll")                                                                       \
        for (int j = 0; j < 2; ++j) b[j] = *(const short8*)&Bs[B][wn * 32 + j * 16 + l15][ca];  \
        if ((KN) < EMB) GO_STAGE(B ^ 1, KN)                                                     \
        _Pragma("unroll")                                                                       \
        for (int i = 0; i < 4; ++i)                                                             \
            _Pragma("unroll")                                                                   \
            for (int j = 0; j < 2; ++j)                                                         \
                acc[i][j] = MFMA16(a[i], b[j], acc[i][j]);                                      \
        __syncthreads();                                                                        \
    }

    GO_STAGE(0, 0)
    __syncthreads();
    for (int k0 = 0; k0 < EMB; k0 += 64) {
        GO_STEP(0, k0 + 32)
        GO_STEP(1, k0 + 64)
    }
#pragma unroll
    for (int i = 0; i < 4; ++i)
#pragma unroll
        for (int j = 0; j < 2; ++j)
#pragma unroll
            for (int r = 0; r < 4; ++r) {
                int m = m0 + wm * 64 + i * 16 + lq * 4 + r;
                int n = n0 + wn * 32 + j * 16 + l15;
                out[(size_t)m * EMB + n] = acc[i][j][r];
            }
}

// ---------------------------------------------------------------------------
// K3: flash attention (causal), 32x32x16, DIRECT-FROM-L2 (R5).
// No K/V LDS staging, no main-loop barriers: K/V per head = 512 KB and the
// XCD-pinned block mapping keeps 4 heads (2 MB) per XCD's 4 MB L2 (m169
// precedent: don't stage what cache-fits). Every wave owns 32 q-rows and an
// independent kv sub-range; fragments (kf/vf/qf, all contiguous 16 B/lane)
// are loaded straight from global with register double-buffered kf prefetch,
// so each wave is a free-running pipeline (QK chain of tile t overlaps PV of
// t-1 purely via scheduler, 3-4 waves/SIMD via the kv-split below).
// kv-split: waves (2p, 2p+1) share q-group g: lo wave does kv chunks
// [0,nlo), hi wave [nlo,g) plus the diagonal chunk g (fixed-shift softmax
// => partial O/l add exactly). One LDS combine (16.5 KB) + single barrier.
// Validated 32x32 data path from R3/R4: S^T = K*Q^T, P via cvt_pk +
// permlane32_swap in-register, fp32 lsum, bpermute-free epilogue.
// Grid 1024 x 256thr; XCD-pin: xcd = n&7 -> bh = xcd*4 + (s&3); heavy-first.
// ---------------------------------------------------------------------------
#define LOAD_KF(DST, C)                                                                        \
    _Pragma("unroll")                                                                          \
    for (int ks = 0; ks < 4; ++ks)                                                             \
        DST[ks] = *(const short8*)&Kb[(size_t)((C) * 32 + l31) * HD + ks * 16 + hi * 8];

#define LOAD_VF(DST, C)                                                                        \
    _Pragma("unroll")                                                                          \
    for (int s_ = 0; s_ < 2; ++s_) {                                                           \
        DST[s_]     = *(const short8*)&Vb[(size_t)l31 * S_LEN + (C) * 32 + s_ * 16 + hi * 8];  \
        DST[2 + s_] = *(const short8*)&Vb[(size_t)(32 + l31) * S_LEN + (C) * 32 + s_ * 16 + hi * 8]; \
    }

// exp2 + lsum + bf16-pack + half_swap: one 32-kv block of scores -> 2 A-frags
#define SM_PACK(SC, PA, PB)                                                                    \
    {                                                                                           \
        float e0 = EXP2(SC[0]),  e1 = EXP2(SC[1]),  e2 = EXP2(SC[2]),  e3 = EXP2(SC[3]);        \
        float e4 = EXP2(SC[4]),  e5 = EXP2(SC[5]),  e6 = EXP2(SC[6]),  e7 = EXP2(SC[7]);        \
        float e8 = EXP2(SC[8]),  e9 = EXP2(SC[9]),  eA = EXP2(SC[10]), eB = EXP2(SC[11]);       \
        float eC = EXP2(SC[12]), eD = EXP2(SC[13]), eE = EXP2(SC[14]), eF = EXP2(SC[15]);       \
        lsum += (((e0 + e1) + (e2 + e3)) + ((e4 + e5) + (e6 + e7)))                             \
              + (((e8 + e9) + (eA + eB)) + ((eC + eD) + (eE + eF)));                            \
        u32 a0 = pkbf(e0, e1), a1 = pkbf(e2, e3);                                               \
        u32 a2 = pkbf(e4, e5), a3 = pkbf(e6, e7);                                               \
        u32 a4 = pkbf(e8, e9), a5 = pkbf(eA, eB);                                               \
        u32 a6 = pkbf(eC, eD), a7 = pkbf(eE, eF);                                               \
        u32 w0, w2, w1, w3, x0, x2, x1, x3;                                                     \
        half_swap(a0, a2, w0, w2);                                                              \
        half_swap(a1, a3, w1, w3);                                                              \
        half_swap(a4, a6, x0, x2);                                                              \
        half_swap(a5, a7, x1, x3);                                                              \
        union { u32 u[4]; short8 s8; } f0_, f1_;                                                \
        f0_.u[0] = w0; f0_.u[1] = w1; f0_.u[2] = w2; f0_.u[3] = w3;                             \
        f1_.u[0] = x0; f1_.u[1] = x1; f1_.u[2] = x2; f1_.u[3] = x3;                             \
        PA = f0_.s8; PB = f1_.s8;                                                               \
    }

// one 32-kv chunk: vf issued first (hidden under QK+SM), QK 4-chain, mask
// (diag only), softmax-pack, PV 4 MFMA.
#define ATTN_CHUNK(KF, C, DIAG)                                                                \
    {                                                                                           \
        short8 vf[4];                                                                           \
        LOAD_VF(vf, C)                                                                          \
        f32x16 sc = {};                                                                         \
        __builtin_amdgcn_s_setprio(1);                                                          \
        sc = MFMA32(KF[0], qf[0], sc);                                                          \
        sc = MFMA32(KF[1], qf[1], sc);                                                          \
        sc = MFMA32(KF[2], qf[2], sc);                                                          \
        sc = MFMA32(KF[3], qf[3], sc);                                                          \
        __builtin_amdgcn_s_setprio(0);                                                          \
        if (DIAG) {                                                                             \
            _Pragma("unroll")                                                                   \
            for (int r = 0; r < 16; ++r)                                                        \
                if ((r & 3) + 8 * (r >> 2) + 4 * hi > l31) sc[r] = -__builtin_inff();           \
        }                                                                                       \
        short8 pa0, pa1;                                                                        \
        SM_PACK(sc, pa0, pa1)                                                                   \
        __builtin_amdgcn_s_setprio(1);                                                          \
        acc0 = MFMA32(pa0, vf[0], acc0);                                                        \
        acc1 = MFMA32(pa0, vf[2], acc1);                                                        \
        acc0 = MFMA32(pa1, vf[1], acc0);                                                        \
        acc1 = MFMA32(pa1, vf[3], acc1);                                                        \
        __builtin_amdgcn_s_setprio(0);                                                          \
    }

__global__ __launch_bounds__(256, 3) void attn_kernel(
    const u16* __restrict__ Q, const u16* __restrict__ K,
    const u16* __restrict__ Vt, u16* __restrict__ ctx) {
    const int tid = threadIdx.x;
    const int lane = tid & 63, wid = tid >> 6;   // 4 waves/block
    const int l31 = lane & 31, hi = lane >> 5;
    const int pairid = wid >> 1, half = wid & 1; // (q-group within block, kv half)

    const int n = blockIdx.x;
    const int xcd = n & 7, s = n >> 3;           // s: 0..127
    const int bh = xcd * 4 + (s & 3);            // 4 heads pinned per XCD (2 MB K/V)
    const int blk = s >> 2;                      // 0..31, dispatch order = heavy first
    const int b = bh >> 4, h = bh & 15;
    const int g = 62 - 2 * blk + pairid;         // q-group 0..63 (32 rows each)
    const int qw = g * 32;

    const u16* Qb = Q + (size_t)bh * S_LEN * HD;
    const u16* Kb = K + (size_t)bh * S_LEN * HD;
    const u16* Vb = Vt + (size_t)bh * HD * S_LEN;

    __shared__ float Os[2][32][64];   // lo-wave partial O per pair (16 KB)
    __shared__ float LsS[2][2][32];   // [pair][half][q] partial row-sums (512 B)

    // Q B-frags (n = l31 = q row, k(d) = ks*16 + hi*8 + j)
    short8 qf[4];
#pragma unroll
    for (int ks = 0; ks < 4; ++ks)
        qf[ks] = *(const short8*)&Qb[(size_t)(qw + l31) * HD + ks * 16 + hi * 8];

    f32x16 acc0 = {}, acc1 = {};   // O[32q][d0-31], O[32q][d32-63] (partial)
    float lsum = 0.f;              // partial row-sum for q = l31 (this hi-half)

    // kv chunk range for this wave: lo = [0,nlo), hi = [nlo,g) + diag chunk g
    const int nlo = (g + 1) >> 1;
    const int c0 = half ? nlo : 0;
    const int c1 = half ? g : nlo;

    short8 kfA[4], kfB[4];
    int c = c0;
    if (c < c1) LOAD_KF(kfA, c)
    for (; c + 2 <= c1; c += 2) {
        LOAD_KF(kfB, c + 1)
        ATTN_CHUNK(kfA, c, 0)
        if (c + 2 < c1) LOAD_KF(kfA, c + 2)
        ATTN_CHUNK(kfB, c + 1, 0)
    }
    if (c < c1) ATTN_CHUNK(kfA, c, 0)
    if (half) {                                  // diagonal chunk (masked)
        short8 kfD[4];
        LOAD_KF(kfD, g)
        ATTN_CHUNK(kfD, g, 1)
    }

    // combine half-lanes of lsum (lanes l and l^32 hold partials for q=l31)
    union { float f; u32 u; } lu; lu.f = lsum;
    u32 ra, rb;
    half_swap(lu.u, lu.u, ra, rb);
    union { u32 u; float f; } ua, ub; ua.u = ra; ub.u = rb;
    float tot = ua.f + ub.f;

    LsS[pairid][half][l31] = tot;                // both hi-halves write same value
    if (half == 0) {
#pragma unroll
        for (int r = 0; r < 16; ++r) {
            int q = (r & 3) + 8 * (r >> 2) + 4 * hi;
            Os[pairid][q][l31]      = acc0[r];
            Os[pairid][q][32 + l31] = acc1[r];
        }
    }
    __syncthreads();
    if (half == 1) {
#pragma unroll
        for (int r = 0; r < 16; ++r) {
            int q = (r & 3) + 8 * (r >> 2) + 4 * hi;
            float o0 = acc0[r] + Os[pairid][q][l31];
            float o1 = acc1[r] + Os[pairid][q][32 + l31];
            float lr = 1.f / (LsS[pairid][0][q] + LsS[pairid][1][q]);
            size_t base = ((size_t)b * S_LEN + (qw + q)) * EMB + h * HD;
            ctx[base + l31]      = f2bf(o0 * lr);
            ctx[base + 32 + l31] = f2bf(o1 * lr);
        }
    }
}

// ---------------------------------------------------------------------------
extern "C" void kernel_launch(void* const* d_in, const int* in_sizes, int n_in,
                              void* d_out, int out_size, void* d_ws, size_t ws_size,
                              hipStream_t stream) {
    const float* x  = (const float*)d_in[0];
    const float* wq = (const float*)d_in[1];
    const float* wk = (const float*)d_in[2];
    const float* wv = (const float*)d_in[3];
    const float* wo = (const float*)d_in[4];
    float* out = (float*)d_out;

    u16* ws  = (u16*)d_ws;
    u16* xb  = ws;                             // 4M : x bf16
    u16* Wt  = xb  + (size_t)4 * 1024 * 1024;  // 4M : 4 transposed weights
    u16* Qb  = Wt  + (size_t)4 * 1024 * 1024;  // 4M : Q [B,H,S,D] (pre-scaled)
    u16* Kb  = Qb  + (size_t)4 * 1024 * 1024;  // 4M : K [B,H,S,D]
    u16* Vtb = Kb  + (size_t)4 * 1024 * 1024;  // 4M : V^T [B,H,D,S]
    u16* ctx = Vtb + (size_t)4 * 1024 * 1024;  // 4M : ctx [B,S,E]

    prep_kernel<<<dim3(32, 32, 8), dim3(256), 0, stream>>>(x, wq, wk, wv, wo, xb, Wt);
    gemm_proj_kernel<<<dim3(8, 32, 3), dim3(256), 0, stream>>>(xb, Wt, Qb, Kb, Vtb);
    attn_kernel<<<dim3(1024), dim3(256), 0, stream>>>(Qb, Kb, Vtb, ctx);
    gemm_out_kernel<<<dim3(16, 32), dim3(256), 0, stream>>>(ctx, Wt + (size_t)3 * 1024 * 1024, out);
}

// Round 6
// 177.276 us; speedup vs baseline: 1.1717x; 1.1717x over previous
//
#include <hip/hip_runtime.h>
#include <hip/hip_bf16.h>

#define S_LEN 2048
#define EMB   1024
#define NH    16
#define HD    64
#define BATCH 2
#define MROWS (BATCH * S_LEN)   // 4096

typedef __attribute__((ext_vector_type(8))) short short8;   // 8 bf16 = 4 VGPR
typedef __attribute__((ext_vector_type(4))) float float4v;  // 4 fp32

#define MFMA16(a, b, c) __builtin_amdgcn_mfma_f32_16x16x32_bf16((a), (b), (c), 0, 0, 0)

typedef unsigned short u16;
typedef unsigned int   u32;

__device__ __forceinline__ u16 f2bf(float f) {
    union { float f; u32 u; } v; v.f = f;
    u32 u = v.u;
    return (u16)((u + 0x7fffu + ((u >> 16) & 1u)) >> 16);  // RNE
}

// packed fp32x2 -> bf16x2 (HW RNE on gfx950; fallback manual)
#if __has_builtin(__builtin_amdgcn_cvt_pk_bf16_f32)
typedef __attribute__((ext_vector_type(2))) __bf16 bfx2;
__device__ __forceinline__ u32 pkbf(float a, float b) {
    union { bfx2 v; u32 u; } c;
    c.v = __builtin_amdgcn_cvt_pk_bf16_f32(a, b);
    return c.u;
}
#else
__device__ __forceinline__ u32 pkbf(float a, float b) {
    return (u32)f2bf(a) | ((u32)f2bf(b) << 16);
}
#endif

#if __has_builtin(__builtin_amdgcn_exp2f)
#define EXP2(x) __builtin_amdgcn_exp2f(x)
#else
#define EXP2(x) exp2f(x)
#endif

// async 16B global->LDS (lds dest = wave-uniform base + lane*16)
typedef __attribute__((address_space(3))) unsigned char lds_u8;
typedef __attribute__((address_space(1))) const unsigned char glb_u8;
__device__ __forceinline__ void async_copy16(const void* g, void* l) {
    __builtin_amdgcn_global_load_lds((glb_u8*)g, (lds_u8*)l, 16, 0, 0);
}

// ---------------------------------------------------------------------------
// K0: fused prologue. z=0..3: convert+transpose weight z (Wq pre-scaled by
// 0.125*log2e so QK scores exit the MFMA in exp2 domain). z=4..7: x -> bf16.
// ---------------------------------------------------------------------------
__global__ __launch_bounds__(256) void prep_kernel(
    const float* __restrict__ x,
    const float* __restrict__ W0, const float* __restrict__ W1,
    const float* __restrict__ W2, const float* __restrict__ W3,
    u16* __restrict__ xb, u16* __restrict__ Wt) {
    const int z = blockIdx.z;
    const int tid = threadIdx.x;
    if (z >= 4) {
        int i = ((((z - 4) * 1024) + blockIdx.y * 32 + blockIdx.x) * 256 + tid) * 4;
        float4 f = *(const float4*)(x + i);
        uint2 o; o.x = pkbf(f.x, f.y); o.y = pkbf(f.z, f.w);
        *(uint2*)(xb + i) = o;
        return;
    }
    const float* W = (z == 0) ? W0 : (z == 1) ? W1 : (z == 2) ? W2 : W3;
    u16* dst = Wt + (size_t)z * EMB * EMB;
    const float sc = (z == 0) ? 0.18033688011112042f : 1.0f;
    __shared__ float tile[32][33];
    int c0 = blockIdx.x * 32, r0 = blockIdx.y * 32;
    int tx = tid & 31, ty = tid >> 5;
#pragma unroll
    for (int i = 0; i < 4; ++i)
        tile[ty + 8 * i][tx] = W[(size_t)(r0 + ty + 8 * i) * EMB + c0 + tx];
    __syncthreads();
#pragma unroll
    for (int i = 0; i < 4; ++i)
        dst[(size_t)(c0 + ty + 8 * i) * EMB + r0 + tx] = f2bf(tile[tx][ty + 8 * i] * sc);
}

// ---------------------------------------------------------------------------
// GEMM core (128x128): BK=32, depth-1 LDS double-buffer, xor swizzle
// s(row)=(row>>1)&3 (2-way on banks = free). Prefetch before MFMAs.
// ---------------------------------------------------------------------------
#define GEMM_STEP(B, KN)                                                                       \
    {                                                                                           \
        short8 a[4], b[4];                                                                      \
        _Pragma("unroll")                                                                       \
        for (int i = 0; i < 4; ++i) a[i] = *(const short8*)&As[B][wm * 64 + i * 16 + l15][ca];  \
        _Pragma("unroll")                                                                       \
        for (int j = 0; j < 4; ++j) b[j] = *(const short8*)&Bs[B][wn * 64 + j * 16 + l15][ca];  \
        if ((KN) < EMB) {                                                                       \
            for (int wl = wid; wl < 8; wl += 4) {                                               \
                async_copy16(&Ag[(size_t)(m0 + wl * 16 + rr) * EMB + (KN) + cc], &As[B ^ 1][wl * 16][0]); \
                async_copy16(&Bg[(size_t)(n0 + wl * 16 + rr) * EMB + (KN) + cc], &Bs[B ^ 1][wl * 16][0]); \
            }                                                                                   \
        }                                                                                       \
        _Pragma("unroll")                                                                       \
        for (int i = 0; i < 4; ++i)                                                             \
            _Pragma("unroll")                                                                   \
            for (int j = 0; j < 4; ++j)                                                         \
                acc[i][j] = MFMA16(a[i], b[j], acc[i][j]);                                      \
        __syncthreads();                                                                        \
    }

#define GEMM_CORE(A_, B_)                                                                      \
    const int tid = threadIdx.x;                                                                \
    const int lane = tid & 63, wid = tid >> 6;                                                  \
    const int wm = wid >> 1, wn = wid & 1;                                                      \
    const int l15 = lane & 15, lq = lane >> 4;                                                  \
    const int m0 = blockIdx.y * 128, n0 = blockIdx.x * 128;                                     \
    const u16* Ag = (A_);                                                                       \
    const u16* Bg = (B_);                                                                       \
    __shared__ u16 As[2][128][32];                                                              \
    __shared__ u16 Bs[2][128][32];                                                              \
    float4v acc[4][4] = {};                                                                     \
    const int rr = lane >> 2;                                                                   \
    const int cc = ((lane & 3) ^ ((rr >> 1) & 3)) * 8;                                          \
    const int ca = (lq ^ ((l15 >> 1) & 3)) * 8;                                                 \
    for (int wl = wid; wl < 8; wl += 4) {                                                       \
        async_copy16(&Ag[(size_t)(m0 + wl * 16 + rr) * EMB + cc], &As[0][wl * 16][0]);          \
        async_copy16(&Bg[(size_t)(n0 + wl * 16 + rr) * EMB + cc], &Bs[0][wl * 16][0]);          \
    }                                                                                           \
    __syncthreads();                                                                            \
    for (int k0 = 0; k0 < EMB; k0 += 64) {                                                      \
        GEMM_STEP(0, k0 + 32)                                                                   \
        GEMM_STEP(1, k0 + 64)                                                                   \
    }

// K2: fused 3-projection GEMM: z=0 Q[B,H,S,D], z=1 K[B,H,S,D], z=2 V^T[B,H,D,S]
__global__ __launch_bounds__(256) void gemm_proj_kernel(
    const u16* __restrict__ A, const u16* __restrict__ WtAll,
    u16* __restrict__ Qb, u16* __restrict__ Kb, u16* __restrict__ Vtb) {
    const int z = blockIdx.z;
    const u16* Wt = WtAll + (size_t)z * EMB * EMB;
    GEMM_CORE(A, Wt)
#pragma unroll
    for (int i = 0; i < 4; ++i)
#pragma unroll
        for (int j = 0; j < 4; ++j) {
            int mb = m0 + wm * 64 + i * 16 + lq * 4;      // 4 consecutive m
            int n  = n0 + wn * 64 + j * 16 + l15;
            int b_ = mb >> 11, s = mb & 2047;
            int h = n >> 6, d = n & 63;
            if (z == 2) {
                uint2 pv;
                pv.x = pkbf(acc[i][j][0], acc[i][j][1]);
                pv.y = pkbf(acc[i][j][2], acc[i][j][3]);
                *(uint2*)&Vtb[(((size_t)(b_ * NH + h) * HD + d) * S_LEN) + s] = pv;
            } else {
                u16* dst = (z == 1) ? Kb : Qb;
#pragma unroll
                for (int r = 0; r < 4; ++r)
                    dst[(((size_t)(b_ * NH + h) * S_LEN + s + r) * HD) + d] = f2bf(acc[i][j][r]);
            }
        }
}

// ---------------------------------------------------------------------------
// K4: output GEMM -> fp32. 128m x 64n tiles: grid (16,32) = 512 blocks.
// ---------------------------------------------------------------------------
__global__ __launch_bounds__(256) void gemm_out_kernel(
    const u16* __restrict__ A, const u16* __restrict__ Wt, float* __restrict__ out) {
    const int tid = threadIdx.x;
    const int lane = tid & 63, wid = tid >> 6;
    const int wm = wid >> 1, wn = wid & 1;
    const int l15 = lane & 15, lq = lane >> 4;
    const int m0 = blockIdx.y * 128, n0 = blockIdx.x * 64;
    __shared__ u16 As[2][128][32];
    __shared__ u16 Bs[2][64][32];
    float4v acc[4][2] = {};
    const int rr = lane >> 2;
    const int cc = ((lane & 3) ^ ((rr >> 1) & 3)) * 8;
    const int ca = (lq ^ ((l15 >> 1) & 3)) * 8;

#define GO_STAGE(B, KN)                                                                        \
    {                                                                                           \
        for (int wl = wid; wl < 8; wl += 4)                                                     \
            async_copy16(&A[(size_t)(m0 + wl * 16 + rr) * EMB + (KN) + cc], &As[B][wl * 16][0]);\
        async_copy16(&Wt[(size_t)(n0 + wid * 16 + rr) * EMB + (KN) + cc], &Bs[B][wid * 16][0]); \
    }
#define GO_STEP(B, KN)                                                                         \
    {                                                                                           \
        short8 a[4], b[2];                                                                      \
        _Pragma("unroll")                                                                       \
        for (int i = 0; i < 4; ++i) a[i] = *(const short8*)&As[B][wm * 64 + i * 16 + l15][ca];  \
        _Pragma("unroll")                                                                       \
        for (int j = 0; j < 2; ++j) b[j] = *(const short8*)&Bs[B][wn * 32 + j * 16 + l15][ca];  \
        if ((KN) < EMB) GO_STAGE(B ^ 1, KN)                                                     \
        _Pragma("unroll")                                                                       \
        for (int i = 0; i < 4; ++i)                                                             \
            _Pragma("unroll")                                                                   \
            for (int j = 0; j < 2; ++j)                                                         \
                acc[i][j] = MFMA16(a[i], b[j], acc[i][j]);                                      \
        __syncthreads();                                                                        \
    }

    GO_STAGE(0, 0)
    __syncthreads();
    for (int k0 = 0; k0 < EMB; k0 += 64) {
        GO_STEP(0, k0 + 32)
        GO_STEP(1, k0 + 64)
    }
#pragma unroll
    for (int i = 0; i < 4; ++i)
#pragma unroll
        for (int j = 0; j < 2; ++j)
#pragma unroll
            for (int r = 0; r < 4; ++r) {
                int m = m0 + wm * 64 + i * 16 + lq * 4 + r;
                int n = n0 + wn * 32 + j * 16 + l15;
                out[(size_t)m * EMB + n] = acc[i][j][r];
            }
}

// ---------------------------------------------------------------------------
// K3: flash attention (causal), S^T = K*Q^T, fixed-shift softmax (m=0).
// R6 = R1 (best-measured structure, ~42us) + T5 s_setprio around the MFMA
// clusters. R2-R5 structural rewrites (pipelined PV / 32x32 / parity-split /
// direct-L2) all regressed vs this structure; reverting to it exactly.
// setprio mechanism (m191): with 2 independent blocks/CU (16 y-pairs per
// XCD-pinned bh), co-resident waves sit at different phases -> boosting the
// MFMA-issuing wave's priority preempts other blocks' staging VALU/loads.
// Paired-concurrent q-tiles: block (bh, y) owns qa = y (light) and
// qh = 31-y (heavy): 33 tile-units/block, perfectly balanced grid of 512.
// For kv tiles t <= qa BOTH q-sets share the same kf/vf LDS reads. LDS =
// Ks[2]+Vs[2]+Ps[4][2] = 48 KiB -> 2 blocks/CU sustained.
// ---------------------------------------------------------------------------
#define ATTN_STAGE(B, T)                                                                       \
    {                                                                                           \
        int kv0s = (T) * 64;                                                                    \
        for (int wl = wid; wl < 8; wl += 4) {                                                   \
            async_copy16(&Kb[(size_t)(kv0s + wl * 8 + rr8) * HD + cc8], &Ks[B][wl * 8][0]);     \
            async_copy16(&Vb[(size_t)(wl * 8 + rr8) * S_LEN + kv0s + cc8], &Vs[B][wl * 8][0]);  \
        }                                                                                       \
    }

// QK + mask + exp2 + pack + swizzled Ps write (no drain, no PV)
// PS is a per-wave per-set buffer: u16 (*)[64]
#define ATTN_QKSM(KF, T, QF, PS, QW)                                                           \
    {                                                                                           \
        const int kv0 = (T) * 64;                                                               \
        float4v sc[4];                                                                          \
        __builtin_amdgcn_s_setprio(1);                                                          \
        _Pragma("unroll")                                                                       \
        for (int nt = 0; nt < 4; ++nt) {                                                        \
            float4v c4 = {};                                                                    \
            c4 = MFMA16(KF[nt][0], QF[0], c4);                                                  \
            c4 = MFMA16(KF[nt][1], QF[1], c4);                                                  \
            sc[nt] = c4;                                                                        \
        }                                                                                       \
        __builtin_amdgcn_s_setprio(0);                                                          \
        if (kv0 + 63 > (QW)) {                                                                  \
            const int qi = (QW) + l15;                                                          \
            _Pragma("unroll")                                                                   \
            for (int nt = 0; nt < 4; ++nt)                                                      \
                _Pragma("unroll")                                                               \
                for (int r = 0; r < 4; ++r)                                                     \
                    if (kv0 + nt * 16 + lq * 4 + r > qi) sc[nt][r] = -__builtin_inff();         \
        }                                                                                       \
        _Pragma("unroll")                                                                       \
        for (int nt = 0; nt < 4; ++nt) {                                                        \
            float p0 = EXP2(sc[nt][0]);                                                         \
            float p1 = EXP2(sc[nt][1]);                                                         \
            float p2 = EXP2(sc[nt][2]);                                                         \
            float p3 = EXP2(sc[nt][3]);                                                         \
            uint2 pk;                                                                           \
            pk.x = pkbf(p0, p1);                                                                \
            pk.y = pkbf(p2, p3);                                                                \
            /* chunk-space write: chunk = nt*2+(lq>>1), sub-8B = lq&1, ^swp */                  \
            *(uint2*)((char*)&PS[l15][0] +                                                      \
                      (((nt * 2 + (lq >> 1)) ^ swp) * 16 + (lq & 1) * 8)) = pk;                 \
        }                                                                                       \
    }

#define ATTN_PV(PS, VF, OO, LS)                                                                \
    {                                                                                           \
        __builtin_amdgcn_s_setprio(1);                                                          \
        _Pragma("unroll")                                                                       \
        for (int kk = 0; kk < 2; ++kk) {                                                        \
            /* chunk-space read: chunk = kk*4+lq, ^swp (same mapping) */                        \
            short8 pf = *(const short8*)((const char*)&PS[l15][0] +                             \
                                         (((kk * 4 + lq) ^ swp) * 16));                         \
            _Pragma("unroll")                                                                   \
            for (int nd = 0; nd < 4; ++nd)                                                      \
                OO[nd] = MFMA16(pf, VF[kk][nd], OO[nd]);                                        \
            LS = MFMA16(pf, ones8, LS);                                                         \
        }                                                                                       \
        __builtin_amdgcn_s_setprio(0);                                                          \
    }

#define ATTN_TILE(B, T)                                                                        \
    {                                                                                           \
        if ((T) + 1 < ntiles) ATTN_STAGE(B ^ 1, (T) + 1)                                        \
        short8 kf[4][2];                                                                        \
        _Pragma("unroll")                                                                       \
        for (int nt = 0; nt < 4; ++nt) {                                                        \
            int r_ = nt * 16 + l15;                                                             \
            int sw = r_ & 7;                                                                    \
            kf[nt][0] = *(const short8*)&Ks[B][r_][(lq ^ sw) * 8];                              \
            kf[nt][1] = *(const short8*)&Ks[B][r_][((lq + 4) ^ sw) * 8];                        \
        }                                                                                       \
        short8 vf[2][4];                                                                        \
        _Pragma("unroll")                                                                       \
        for (int kk = 0; kk < 2; ++kk)                                                          \
            _Pragma("unroll")                                                                   \
            for (int nd = 0; nd < 4; ++nd) {                                                    \
                int d = nd * 16 + l15;                                                          \
                vf[kk][nd] = *(const short8*)&Vs[B][d][((kk * 4 + lq) ^ (d & 7)) * 8];          \
            }                                                                                   \
        ATTN_QKSM(kf, T, qfh, PsH, qwh)                                                         \
        if ((T) <= qa) ATTN_QKSM(kf, T, qfa, PsA, qwa)                                          \
        asm volatile("s_waitcnt lgkmcnt(0)" ::: "memory");                                      \
        ATTN_PV(PsH, vf, Oh, lsh)                                                               \
        if ((T) <= qa) ATTN_PV(PsA, vf, Oa, lsa)                                                \
        __syncthreads();                                                                        \
    }

#define ATTN_EPI(OO, LS, Q0)                                                                   \
    {                                                                                           \
        _Pragma("unroll")                                                                       \
        for (int r = 0; r < 4; ++r) {                                                           \
            float lr = 1.f / LS[r];                                                             \
            int s = (Q0) + wid * 16 + lq * 4 + r;                                               \
            size_t base = ((size_t)b * S_LEN + s) * EMB + h * HD;                               \
            _Pragma("unroll")                                                                   \
            for (int nd = 0; nd < 4; ++nd)                                                      \
                ctx[base + nd * 16 + l15] = f2bf(OO[nd][r] * lr);                               \
        }                                                                                       \
    }

__global__ __launch_bounds__(256, 2) void attn_kernel(
    const u16* __restrict__ Q, const u16* __restrict__ K,
    const u16* __restrict__ Vt, u16* __restrict__ ctx) {
    const int tid = threadIdx.x;
    const int lane = tid & 63, wid = tid >> 6;
    const int l15 = lane & 15, lq = lane >> 4;
    const int bh = blockIdx.x;               // x fastest: same-bh blocks same XCD
    const int b = bh >> 4, h = bh & 15;
    const int y = blockIdx.y;                // 0..15
    const int qa = y, qh = 31 - y;           // paired q-tiles: 33 units/block
    const int q0h = qh * 64, q0a = qa * 64;
    const int qwh = q0h + wid * 16, qwa = q0a + wid * 16;

    const u16* Qb = Q + (size_t)bh * S_LEN * HD;
    const u16* Kb = K + (size_t)bh * S_LEN * HD;
    const u16* Vb = Vt + (size_t)bh * HD * S_LEN;

    __shared__ u16 Ks[2][64][64];      // [kv][d], xor-swizzled chunks (16 KB)
    __shared__ u16 Vs[2][64][64];      // [d][kv], xor-swizzled chunks (16 KB)
    __shared__ u16 Ps[4][2][16][64];   // per-wave, per-set P, chunk-swizzled (16 KB)
    // total LDS = 49152 B -> 2 blocks/CU sustained (grid 512 = 2/CU exactly)

    u16 (*PsH)[64] = Ps[wid][0];
    u16 (*PsA)[64] = Ps[wid][1];

    const int rr8 = lane >> 3;
    const int cc8 = ((lane & 7) ^ rr8) * 8;  // s(row)=row&7
    const int swp = l15 & 7;                 // Ps chunk swizzle key

    // ones column for MFMA row-sum (bf16 1.0 = 0x3F80)
    short8 ones8;
#pragma unroll
    for (int i = 0; i < 8; ++i) ones8[i] = (short)0x3F80;

    // Q fragments for both q-sets (B-operand layout: lane n=l15 q-row, k=lq*8+j)
    short8 qfh[2], qfa[2];
#pragma unroll
    for (int ks = 0; ks < 2; ++ks) {
        qfh[ks] = *(const short8*)&Qb[(size_t)(qwh + l15) * HD + ks * 32 + lq * 8];
        qfa[ks] = *(const short8*)&Qb[(size_t)(qwa + l15) * HD + ks * 32 + lq * 8];
    }

    float4v Oh[4] = {}, Oa[4] = {};
    float4v lsh = {}, lsa = {};

    const int ntiles = qh + 1;               // 17..32
    ATTN_STAGE(0, 0)
    __syncthreads();
    for (int t = 0; t < ntiles; t += 2) {
        ATTN_TILE(0, t)
        if (t + 1 < ntiles) ATTN_TILE(1, t + 1)
    }

    ATTN_EPI(Oh, lsh, q0h)
    ATTN_EPI(Oa, lsa, q0a)
}

// ---------------------------------------------------------------------------
extern "C" void kernel_launch(void* const* d_in, const int* in_sizes, int n_in,
                              void* d_out, int out_size, void* d_ws, size_t ws_size,
                              hipStream_t stream) {
    const float* x  = (const float*)d_in[0];
    const float* wq = (const float*)d_in[1];
    const float* wk = (const float*)d_in[2];
    const float* wv = (const float*)d_in[3];
    const float* wo = (const float*)d_in[4];
    float* out = (float*)d_out;

    u16* ws  = (u16*)d_ws;
    u16* xb  = ws;                             // 4M : x bf16
    u16* Wt  = xb  + (size_t)4 * 1024 * 1024;  // 4M : 4 transposed weights
    u16* Qb  = Wt  + (size_t)4 * 1024 * 1024;  // 4M : Q [B,H,S,D] (pre-scaled)
    u16* Kb  = Qb  + (size_t)4 * 1024 * 1024;  // 4M : K [B,H,S,D]
    u16* Vtb = Kb  + (size_t)4 * 1024 * 1024;  // 4M : V^T [B,H,D,S]
    u16* ctx = Vtb + (size_t)4 * 1024 * 1024;  // 4M : ctx [B,S,E]

    prep_kernel<<<dim3(32, 32, 8), dim3(256), 0, stream>>>(x, wq, wk, wv, wo, xb, Wt);
    gemm_proj_kernel<<<dim3(8, 32, 3), dim3(256), 0, stream>>>(xb, Wt, Qb, Kb, Vtb);
    attn_kernel<<<dim3(32, 16), dim3(256), 0, stream>>>(Qb, Kb, Vtb, ctx);
    gemm_out_kernel<<<dim3(16, 32), dim3(256), 0, stream>>>(ctx, Wt + (size_t)3 * 1024 * 1024, out);
}

// Round 9
// 174.442 us; speedup vs baseline: 1.1907x; 1.0162x over previous
//
#include <hip/hip_runtime.h>
#include <hip/hip_bf16.h>

#define S_LEN 2048
#define EMB   1024
#define NH    16
#define HD    64
#define BATCH 2
#define MROWS (BATCH * S_LEN)   // 4096

typedef __attribute__((ext_vector_type(8))) short short8;   // 8 bf16 = 4 VGPR
typedef __attribute__((ext_vector_type(4))) float float4v;  // 4 fp32

#define MFMA16(a, b, c) __builtin_amdgcn_mfma_f32_16x16x32_bf16((a), (b), (c), 0, 0, 0)

typedef unsigned short u16;
typedef unsigned int   u32;

__device__ __forceinline__ u16 f2bf(float f) {
    union { float f; u32 u; } v; v.f = f;
    u32 u = v.u;
    return (u16)((u + 0x7fffu + ((u >> 16) & 1u)) >> 16);  // RNE
}

// packed fp32x2 -> bf16x2 (HW RNE on gfx950; fallback manual)
#if __has_builtin(__builtin_amdgcn_cvt_pk_bf16_f32)
typedef __attribute__((ext_vector_type(2))) __bf16 bfx2;
__device__ __forceinline__ u32 pkbf(float a, float b) {
    union { bfx2 v; u32 u; } c;
    c.v = __builtin_amdgcn_cvt_pk_bf16_f32(a, b);
    return c.u;
}
#else
__device__ __forceinline__ u32 pkbf(float a, float b) {
    return (u32)f2bf(a) | ((u32)f2bf(b) << 16);
}
#endif

#if __has_builtin(__builtin_amdgcn_exp2f)
#define EXP2(x) __builtin_amdgcn_exp2f(x)
#else
#define EXP2(x) exp2f(x)
#endif

// async 16B global->LDS (lds dest = wave-uniform base + lane*16)
typedef __attribute__((address_space(3))) unsigned char lds_u8;
typedef __attribute__((address_space(1))) const unsigned char glb_u8;
__device__ __forceinline__ void async_copy16(const void* g, void* l) {
    __builtin_amdgcn_global_load_lds((glb_u8*)g, (lds_u8*)l, 16, 0, 0);
}

// ---------------------------------------------------------------------------
// K0: fused prologue (R9 = R8 resubmitted; R8 hit an infra failure, never
// ran). z=0..3: convert+transpose weight z on 64x64 tiles — float4
// (16 B/lane) reads, LDS [64][65] staging (transposed read 2-way
// bank-aliased = free, m136), uint2 (4 bf16, 8 B/lane) packed stores via
// cvt_pk. Wq pre-scaled by 0.125*log2e. z=4..7: x -> bf16, 16 floats per
// thread. Coverage: 4 z x 256 blk x 256 thr x 16 = 4,194,304 floats = |x|.
// ---------------------------------------------------------------------------
__global__ __launch_bounds__(256) void prep_kernel(
    const float* __restrict__ x,
    const float* __restrict__ W0, const float* __restrict__ W1,
    const float* __restrict__ W2, const float* __restrict__ W3,
    u16* __restrict__ xb, u16* __restrict__ Wt) {
    const int z = blockIdx.z;
    const int tid = threadIdx.x;
    if (z >= 4) {
        int i = ((((z - 4) * 256) + blockIdx.y * 16 + blockIdx.x) * 256 + tid) * 16;
#pragma unroll
        for (int k = 0; k < 4; ++k) {
            float4 f = *(const float4*)(x + i + k * 4);
            uint2 o; o.x = pkbf(f.x, f.y); o.y = pkbf(f.z, f.w);
            *(uint2*)(xb + i + k * 4) = o;
        }
        return;
    }
    const float* W = (z == 0) ? W0 : (z == 1) ? W1 : (z == 2) ? W2 : W3;
    u16* dst = Wt + (size_t)z * EMB * EMB;
    const float sc = (z == 0) ? 0.18033688011112042f : 1.0f;
    __shared__ float tile[64][65];
    const int c0 = blockIdx.x * 64, r0 = blockIdx.y * 64;
    // read: 64 rows x 16 float4-cols; thread (rv = f4 col, rw = row) x4 rows
    const int rv = tid & 15, rw = tid >> 4;
#pragma unroll
    for (int k = 0; k < 4; ++k) {
        int row = rw + 16 * k;
        float4 f = *(const float4*)&W[(size_t)(r0 + row) * EMB + c0 + rv * 4];
        tile[row][rv * 4 + 0] = f.x;
        tile[row][rv * 4 + 1] = f.y;
        tile[row][rv * 4 + 2] = f.z;
        tile[row][rv * 4 + 3] = f.w;
    }
    __syncthreads();
    // write transposed: out row = original col cr, 4 original rows packed/8B
    const int rq = tid & 15, cw = tid >> 4;
#pragma unroll
    for (int k = 0; k < 4; ++k) {
        int cr = cw + 16 * k;
        float t0 = tile[rq * 4 + 0][cr] * sc;
        float t1 = tile[rq * 4 + 1][cr] * sc;
        float t2 = tile[rq * 4 + 2][cr] * sc;
        float t3 = tile[rq * 4 + 3][cr] * sc;
        uint2 o; o.x = pkbf(t0, t1); o.y = pkbf(t2, t3);
        *(uint2*)&dst[(size_t)(c0 + cr) * EMB + r0 + rq * 4] = o;
    }
}

// ---------------------------------------------------------------------------
// GEMM core (128x128): BK=32, depth-1 LDS double-buffer, xor swizzle
// s(row)=(row>>1)&3 (2-way on banks = free). Prefetch before MFMAs.
// ---------------------------------------------------------------------------
#define GEMM_STEP(B, KN)                                                                       \
    {                                                                                           \
        short8 a[4], b[4];                                                                      \
        _Pragma("unroll")                                                                       \
        for (int i = 0; i < 4; ++i) a[i] = *(const short8*)&As[B][wm * 64 + i * 16 + l15][ca];  \
        _Pragma("unroll")                                                                       \
        for (int j = 0; j < 4; ++j) b[j] = *(const short8*)&Bs[B][wn * 64 + j * 16 + l15][ca];  \
        if ((KN) < EMB) {                                                                       \
            for (int wl = wid; wl < 8; wl += 4) {                                               \
                async_copy16(&Ag[(size_t)(m0 + wl * 16 + rr) * EMB + (KN) + cc], &As[B ^ 1][wl * 16][0]); \
                async_copy16(&Bg[(size_t)(n0 + wl * 16 + rr) * EMB + (KN) + cc], &Bs[B ^ 1][wl * 16][0]); \
            }                                                                                   \
        }                                                                                       \
        _Pragma("unroll")                                                                       \
        for (int i = 0; i < 4; ++i)                                                             \
            _Pragma("unroll")                                                                   \
            for (int j = 0; j < 4; ++j)                                                         \
                acc[i][j] = MFMA16(a[i], b[j], acc[i][j]);                                      \
        __syncthreads();                                                                        \
    }

#define GEMM_CORE(A_, B_)                                                                      \
    const int tid = threadIdx.x;                                                                \
    const int lane = tid & 63, wid = tid >> 6;                                                  \
    const int wm = wid >> 1, wn = wid & 1;                                                      \
    const int l15 = lane & 15, lq = lane >> 4;                                                  \
    const int m0 = blockIdx.y * 128, n0 = blockIdx.x * 128;                                     \
    const u16* Ag = (A_);                                                                       \
    const u16* Bg = (B_);                                                                       \
    __shared__ u16 As[2][128][32];                                                              \
    __shared__ u16 Bs[2][128][32];                                                              \
    float4v acc[4][4] = {};                                                                     \
    const int rr = lane >> 2;                                                                   \
    const int cc = ((lane & 3) ^ ((rr >> 1) & 3)) * 8;                                          \
    const int ca = (lq ^ ((l15 >> 1) & 3)) * 8;                                                 \
    for (int wl = wid; wl < 8; wl += 4) {                                                       \
        async_copy16(&Ag[(size_t)(m0 + wl * 16 + rr) * EMB + cc], &As[0][wl * 16][0]);          \
        async_copy16(&Bg[(size_t)(n0 + wl * 16 + rr) * EMB + cc], &Bs[0][wl * 16][0]);          \
    }                                                                                           \
    __syncthreads();                                                                            \
    for (int k0 = 0; k0 < EMB; k0 += 64) {                                                      \
        GEMM_STEP(0, k0 + 32)                                                                   \
        GEMM_STEP(1, k0 + 64)                                                                   \
    }

// K2: fused 3-projection GEMM: z=0 Q[B,H,S,D], z=1 K[B,H,S,D], z=2 V^T[B,H,D,S]
__global__ __launch_bounds__(256) void gemm_proj_kernel(
    const u16* __restrict__ A, const u16* __restrict__ WtAll,
    u16* __restrict__ Qb, u16* __restrict__ Kb, u16* __restrict__ Vtb) {
    const int z = blockIdx.z;
    const u16* Wt = WtAll + (size_t)z * EMB * EMB;
    GEMM_CORE(A, Wt)
#pragma unroll
    for (int i = 0; i < 4; ++i)
#pragma unroll
        for (int j = 0; j < 4; ++j) {
            int mb = m0 + wm * 64 + i * 16 + lq * 4;      // 4 consecutive m
            int n  = n0 + wn * 64 + j * 16 + l15;
            int b_ = mb >> 11, s = mb & 2047;
            int h = n >> 6, d = n & 63;
            if (z == 2) {
                uint2 pv;
                pv.x = pkbf(acc[i][j][0], acc[i][j][1]);
                pv.y = pkbf(acc[i][j][2], acc[i][j][3]);
                *(uint2*)&Vtb[(((size_t)(b_ * NH + h) * HD + d) * S_LEN) + s] = pv;
            } else {
                u16* dst = (z == 1) ? Kb : Qb;
#pragma unroll
                for (int r = 0; r < 4; ++r)
                    dst[(((size_t)(b_ * NH + h) * S_LEN + s + r) * HD) + d] = f2bf(acc[i][j][r]);
            }
        }
}

// ---------------------------------------------------------------------------
// K4: output GEMM -> fp32. 128m x 64n tiles: grid (16,32) = 512 blocks.
// ---------------------------------------------------------------------------
__global__ __launch_bounds__(256) void gemm_out_kernel(
    const u16* __restrict__ A, const u16* __restrict__ Wt, float* __restrict__ out) {
    const int tid = threadIdx.x;
    const int lane = tid & 63, wid = tid >> 6;
    const int wm = wid >> 1, wn = wid & 1;
    const int l15 = lane & 15, lq = lane >> 4;
    const int m0 = blockIdx.y * 128, n0 = blockIdx.x * 64;
    __shared__ u16 As[2][128][32];
    __shared__ u16 Bs[2][64][32];
    float4v acc[4][2] = {};
    const int rr = lane >> 2;
    const int cc = ((lane & 3) ^ ((rr >> 1) & 3)) * 8;
    const int ca = (lq ^ ((l15 >> 1) & 3)) * 8;

#define GO_STAGE(B, KN)                                                                        \
    {                                                                                           \
        for (int wl = wid; wl < 8; wl += 4)                                                     \
            async_copy16(&A[(size_t)(m0 + wl * 16 + rr) * EMB + (KN) + cc], &As[B][wl * 16][0]);\
        async_copy16(&Wt[(size_t)(n0 + wid * 16 + rr) * EMB + (KN) + cc], &Bs[B][wid * 16][0]); \
    }
#define GO_STEP(B, KN)                                                                         \
    {                                                                                           \
        short8 a[4], b[2];                                                                      \
        _Pragma("unroll")                                                                       \
        for (int i = 0; i < 4; ++i) a[i] = *(const short8*)&As[B][wm * 64 + i * 16 + l15][ca];  \
        _Pragma("unroll")                                                                       \
        for (int j = 0; j < 2; ++j) b[j] = *(const short8*)&Bs[B][wn * 32 + j * 16 + l15][ca];  \
        if ((KN) < EMB) GO_STAGE(B ^ 1, KN)                                                     \
        _Pragma("unroll")                                                                       \
        for (int i = 0; i < 4; ++i)                                                             \
            _Pragma("unroll")                                                                   \
            for (int j = 0; j < 2; ++j)                                                         \
                acc[i][j] = MFMA16(a[i], b[j], acc[i][j]);                                      \
        __syncthreads();                                                                        \
    }

    GO_STAGE(0, 0)
    __syncthreads();
    for (int k0 = 0; k0 < EMB; k0 += 64) {
        GO_STEP(0, k0 + 32)
        GO_STEP(1, k0 + 64)
    }
#pragma unroll
    for (int i = 0; i < 4; ++i)
#pragma unroll
        for (int j = 0; j < 2; ++j)
#pragma unroll
            for (int r = 0; r < 4; ++r) {
                int m = m0 + wm * 64 + i * 16 + lq * 4 + r;
                int n = n0 + wn * 32 + j * 16 + l15;
                out[(size_t)m * EMB + n] = acc[i][j][r];
            }
}

// ---------------------------------------------------------------------------
// K3: flash attention (causal), S^T = K*Q^T, fixed-shift softmax (m=0).
// EXACT R1 structure (best-measured ~42us; R2-R6 variants all neutral or
// regressed). Paired-concurrent q-tiles: block (bh, y) owns qa = y (light)
// and qh = 31-y (heavy): 33 tile-units/block, perfectly balanced grid of
// 512. For kv tiles t <= qa BOTH q-sets share the same kf/vf LDS reads.
// LDS = Ks[2]+Vs[2]+Ps[4][2] = 48 KiB -> 2 blocks/CU sustained.
// ---------------------------------------------------------------------------
#define ATTN_STAGE(B, T)                                                                       \
    {                                                                                           \
        int kv0s = (T) * 64;                                                                    \
        for (int wl = wid; wl < 8; wl += 4) {                                                   \
            async_copy16(&Kb[(size_t)(kv0s + wl * 8 + rr8) * HD + cc8], &Ks[B][wl * 8][0]);     \
            async_copy16(&Vb[(size_t)(wl * 8 + rr8) * S_LEN + kv0s + cc8], &Vs[B][wl * 8][0]);  \
        }                                                                                       \
    }

// QK + mask + exp2 + pack + swizzled Ps write (no drain, no PV)
// PS is a per-wave per-set buffer: u16 (*)[64]
#define ATTN_QKSM(KF, T, QF, PS, QW)                                                           \
    {                                                                                           \
        const int kv0 = (T) * 64;                                                               \
        float4v sc[4];                                                                          \
        _Pragma("unroll")                                                                       \
        for (int nt = 0; nt < 4; ++nt) {                                                        \
            float4v c4 = {};                                                                    \
            c4 = MFMA16(KF[nt][0], QF[0], c4);                                                  \
            c4 = MFMA16(KF[nt][1], QF[1], c4);                                                  \
            sc[nt] = c4;                                                                        \
        }                                                                                       \
        if (kv0 + 63 > (QW)) {                                                                  \
            const int qi = (QW) + l15;                                                          \
            _Pragma("unroll")                                                                   \
            for (int nt = 0; nt < 4; ++nt)                                                      \
                _Pragma("unroll")                                                               \
                for (int r = 0; r < 4; ++r)                                                     \
                    if (kv0 + nt * 16 + lq * 4 + r > qi) sc[nt][r] = -__builtin_inff();         \
        }                                                                                       \
        _Pragma("unroll")                                                                       \
        for (int nt = 0; nt < 4; ++nt) {                                                        \
            float p0 = EXP2(sc[nt][0]);                                                         \
            float p1 = EXP2(sc[nt][1]);                                                         \
            float p2 = EXP2(sc[nt][2]);                                                         \
            float p3 = EXP2(sc[nt][3]);                                                         \
            uint2 pk;                                                                           \
            pk.x = pkbf(p0, p1);                                                                \
            pk.y = pkbf(p2, p3);                                                                \
            /* chunk-space write: chunk = nt*2+(lq>>1), sub-8B = lq&1, ^swp */                  \
            *(uint2*)((char*)&PS[l15][0] +                                                      \
                      (((nt * 2 + (lq >> 1)) ^ swp) * 16 + (lq & 1) * 8)) = pk;                 \
        }                                                                                       \
    }

#define ATTN_PV(PS, VF, OO, LS)                                                                \
    {                                                                                           \
        _Pragma("unroll")                                                                       \
        for (int kk = 0; kk < 2; ++kk) {                                                        \
            /* chunk-space read: chunk = kk*4+lq, ^swp (same mapping) */                        \
            short8 pf = *(const short8*)((const char*)&PS[l15][0] +                             \
                                         (((kk * 4 + lq) ^ swp) * 16));                         \
            _Pragma("unroll")                                                                   \
            for (int nd = 0; nd < 4; ++nd)                                                      \
                OO[nd] = MFMA16(pf, VF[kk][nd], OO[nd]);                                        \
            LS = MFMA16(pf, ones8, LS);                                                         \
        }                                                                                       \
    }

#define ATTN_TILE(B, T)                                                                        \
    {                                                                                           \
        if ((T) + 1 < ntiles) ATTN_STAGE(B ^ 1, (T) + 1)                                        \
        short8 kf[4][2];                                                                        \
        _Pragma("unroll")                                                                       \
        for (int nt = 0; nt < 4; ++nt) {                                                        \
            int r_ = nt * 16 + l15;                                                             \
            int sw = r_ & 7;                                                                    \
            kf[nt][0] = *(const short8*)&Ks[B][r_][(lq ^ sw) * 8];                              \
            kf[nt][1] = *(const short8*)&Ks[B][r_][((lq + 4) ^ sw) * 8];                        \
        }                                                                                       \
        short8 vf[2][4];                                                                        \
        _Pragma("unroll")                                                                       \
        for (int kk = 0; kk < 2; ++kk)                                                          \
            _Pragma("unroll")                                                                   \
            for (int nd = 0; nd < 4; ++nd) {                                                    \
                int d = nd * 16 + l15;                                                          \
                vf[kk][nd] = *(const short8*)&Vs[B][d][((kk * 4 + lq) ^ (d & 7)) * 8];          \
            }                                                                                   \
        ATTN_QKSM(kf, T, qfh, PsH, qwh)                                                         \
        if ((T) <= qa) ATTN_QKSM(kf, T, qfa, PsA, qwa)                                          \
        asm volatile("s_waitcnt lgkmcnt(0)" ::: "memory");                                      \
        ATTN_PV(PsH, vf, Oh, lsh)                                                               \
        if ((T) <= qa) ATTN_PV(PsA, vf, Oa, lsa)                                                \
        __syncthreads();                                                                        \
    }

#define ATTN_EPI(OO, LS, Q0)                                                                   \
    {                                                                                           \
        _Pragma("unroll")                                                                       \
        for (int r = 0; r < 4; ++r) {                                                           \
            float lr = 1.f / LS[r];                                                             \
            int s = (Q0) + wid * 16 + lq * 4 + r;                                               \
            size_t base = ((size_t)b * S_LEN + s) * EMB + h * HD;                               \
            _Pragma("unroll")                                                                   \
            for (int nd = 0; nd < 4; ++nd)                                                      \
                ctx[base + nd * 16 + l15] = f2bf(OO[nd][r] * lr);                               \
        }                                                                                       \
    }

__global__ __launch_bounds__(256, 2) void attn_kernel(
    const u16* __restrict__ Q, const u16* __restrict__ K,
    const u16* __restrict__ Vt, u16* __restrict__ ctx) {
    const int tid = threadIdx.x;
    const int lane = tid & 63, wid = tid >> 6;
    const int l15 = lane & 15, lq = lane >> 4;
    const int bh = blockIdx.x;               // x fastest: same-bh blocks same XCD
    const int b = bh >> 4, h = bh & 15;
    const int y = blockIdx.y;                // 0..15
    const int qa = y, qh = 31 - y;           // paired q-tiles: 33 units/block
    const int q0h = qh * 64, q0a = qa * 64;
    const int qwh = q0h + wid * 16, qwa = q0a + wid * 16;

    const u16* Qb = Q + (size_t)bh * S_LEN * HD;
    const u16* Kb = K + (size_t)bh * S_LEN * HD;
    const u16* Vb = Vt + (size_t)bh * HD * S_LEN;

    __shared__ u16 Ks[2][64][64];      // [kv][d], xor-swizzled chunks (16 KB)
    __shared__ u16 Vs[2][64][64];      // [d][kv], xor-swizzled chunks (16 KB)
    __shared__ u16 Ps[4][2][16][64];   // per-wave, per-set P, chunk-swizzled (16 KB)
    // total LDS = 49152 B -> 2 blocks/CU sustained (grid 512 = 2/CU exactly)

    u16 (*PsH)[64] = Ps[wid][0];
    u16 (*PsA)[64] = Ps[wid][1];

    const int rr8 = lane >> 3;
    const int cc8 = ((lane & 7) ^ rr8) * 8;  // s(row)=row&7
    const int swp = l15 & 7;                 // Ps chunk swizzle key

    // ones column for MFMA row-sum (bf16 1.0 = 0x3F80)
    short8 ones8;
#pragma unroll
    for (int i = 0; i < 8; ++i) ones8[i] = (short)0x3F80;

    // Q fragments for both q-sets (B-operand layout: lane n=l15 q-row, k=lq*8+j)
    short8 qfh[2], qfa[2];
#pragma unroll
    for (int ks = 0; ks < 2; ++ks) {
        qfh[ks] = *(const short8*)&Qb[(size_t)(qwh + l15) * HD + ks * 32 + lq * 8];
        qfa[ks] = *(const short8*)&Qb[(size_t)(qwa + l15) * HD + ks * 32 + lq * 8];
    }

    float4v Oh[4] = {}, Oa[4] = {};
    float4v lsh = {}, lsa = {};

    const int ntiles = qh + 1;               // 17..32
    ATTN_STAGE(0, 0)
    __syncthreads();
    for (int t = 0; t < ntiles; t += 2) {
        ATTN_TILE(0, t)
        if (t + 1 < ntiles) ATTN_TILE(1, t + 1)
    }

    ATTN_EPI(Oh, lsh, q0h)
    ATTN_EPI(Oa, lsa, q0a)
}

// ---------------------------------------------------------------------------
extern "C" void kernel_launch(void* const* d_in, const int* in_sizes, int n_in,
                              void* d_out, int out_size, void* d_ws, size_t ws_size,
                              hipStream_t stream) {
    const float* x  = (const float*)d_in[0];
    const float* wq = (const float*)d_in[1];
    const float* wk = (const float*)d_in[2];
    const float* wv = (const float*)d_in[3];
    const float* wo = (const float*)d_in[4];
    float* out = (float*)d_out;

    u16* ws  = (u16*)d_ws;
    u16* xb  = ws;                             // 4M : x bf16
    u16* Wt  = xb  + (size_t)4 * 1024 * 1024;  // 4M : 4 transposed weights
    u16* Qb  = Wt  + (size_t)4 * 1024 * 1024;  // 4M : Q [B,H,S,D] (pre-scaled)
    u16* Kb  = Qb  + (size_t)4 * 1024 * 1024;  // 4M : K [B,H,S,D]
    u16* Vtb = Kb  + (size_t)4 * 1024 * 1024;  // 4M : V^T [B,H,D,S]
    u16* ctx = Vtb + (size_t)4 * 1024 * 1024;  // 4M : ctx [B,S,E]

    prep_kernel<<<dim3(16, 16, 8), dim3(256), 0, stream>>>(x, wq, wk, wv, wo, xb, Wt);
    gemm_proj_kernel<<<dim3(8, 32, 3), dim3(256), 0, stream>>>(xb, Wt, Qb, Kb, Vtb);
    attn_kernel<<<dim3(32, 16), dim3(256), 0, stream>>>(Qb, Kb, Vtb, ctx);
    gemm_out_kernel<<<dim3(16, 32), dim3(256), 0, stream>>>(ctx, Wt + (size_t)3 * 1024 * 1024, out);
}

// Round 10
// 171.718 us; speedup vs baseline: 1.2096x; 1.0159x over previous
//
#include <hip/hip_runtime.h>
#include <hip/hip_bf16.h>

#define S_LEN 2048
#define EMB   1024
#define NH    16
#define HD    64
#define BATCH 2
#define MROWS (BATCH * S_LEN)   // 4096

typedef __attribute__((ext_vector_type(8))) short short8;   // 8 bf16 = 4 VGPR
typedef __attribute__((ext_vector_type(4))) float float4v;  // 4 fp32

#define MFMA16(a, b, c) __builtin_amdgcn_mfma_f32_16x16x32_bf16((a), (b), (c), 0, 0, 0)

typedef unsigned short u16;
typedef unsigned int   u32;

__device__ __forceinline__ u16 f2bf(float f) {
    union { float f; u32 u; } v; v.f = f;
    u32 u = v.u;
    return (u16)((u + 0x7fffu + ((u >> 16) & 1u)) >> 16);  // RNE
}

// packed fp32x2 -> bf16x2 (HW RNE on gfx950; fallback manual)
#if __has_builtin(__builtin_amdgcn_cvt_pk_bf16_f32)
typedef __attribute__((ext_vector_type(2))) __bf16 bfx2;
__device__ __forceinline__ u32 pkbf(float a, float b) {
    union { bfx2 v; u32 u; } c;
    c.v = __builtin_amdgcn_cvt_pk_bf16_f32(a, b);
    return c.u;
}
#else
__device__ __forceinline__ u32 pkbf(float a, float b) {
    return (u32)f2bf(a) | ((u32)f2bf(b) << 16);
}
#endif

#if __has_builtin(__builtin_amdgcn_exp2f)
#define EXP2(x) __builtin_amdgcn_exp2f(x)
#else
#define EXP2(x) exp2f(x)
#endif

// async 16B global->LDS (lds dest = wave-uniform base + lane*16)
typedef __attribute__((address_space(3))) unsigned char lds_u8;
typedef __attribute__((address_space(1))) const unsigned char glb_u8;
__device__ __forceinline__ void async_copy16(const void* g, void* l) {
    __builtin_amdgcn_global_load_lds((glb_u8*)g, (lds_u8*)l, 16, 0, 0);
}

// ---------------------------------------------------------------------------
// K0: fused prologue (R9-verified). z=0..3: convert+transpose weight z on
// 64x64 tiles — float4 (16 B/lane) reads, LDS [64][65] staging, uint2
// (4 bf16, 8 B/lane) packed stores via cvt_pk. Wq pre-scaled by 0.125*log2e.
// z=4..7: x -> bf16, 16 floats per thread.
// Coverage: 4 z x 256 blk x 256 thr x 16 = 4,194,304 floats = |x|.
// ---------------------------------------------------------------------------
__global__ __launch_bounds__(256) void prep_kernel(
    const float* __restrict__ x,
    const float* __restrict__ W0, const float* __restrict__ W1,
    const float* __restrict__ W2, const float* __restrict__ W3,
    u16* __restrict__ xb, u16* __restrict__ Wt) {
    const int z = blockIdx.z;
    const int tid = threadIdx.x;
    if (z >= 4) {
        int i = ((((z - 4) * 256) + blockIdx.y * 16 + blockIdx.x) * 256 + tid) * 16;
#pragma unroll
        for (int k = 0; k < 4; ++k) {
            float4 f = *(const float4*)(x + i + k * 4);
            uint2 o; o.x = pkbf(f.x, f.y); o.y = pkbf(f.z, f.w);
            *(uint2*)(xb + i + k * 4) = o;
        }
        return;
    }
    const float* W = (z == 0) ? W0 : (z == 1) ? W1 : (z == 2) ? W2 : W3;
    u16* dst = Wt + (size_t)z * EMB * EMB;
    const float sc = (z == 0) ? 0.18033688011112042f : 1.0f;
    __shared__ float tile[64][65];
    const int c0 = blockIdx.x * 64, r0 = blockIdx.y * 64;
    const int rv = tid & 15, rw = tid >> 4;
#pragma unroll
    for (int k = 0; k < 4; ++k) {
        int row = rw + 16 * k;
        float4 f = *(const float4*)&W[(size_t)(r0 + row) * EMB + c0 + rv * 4];
        tile[row][rv * 4 + 0] = f.x;
        tile[row][rv * 4 + 1] = f.y;
        tile[row][rv * 4 + 2] = f.z;
        tile[row][rv * 4 + 3] = f.w;
    }
    __syncthreads();
    const int rq = tid & 15, cw = tid >> 4;
#pragma unroll
    for (int k = 0; k < 4; ++k) {
        int cr = cw + 16 * k;
        float t0 = tile[rq * 4 + 0][cr] * sc;
        float t1 = tile[rq * 4 + 1][cr] * sc;
        float t2 = tile[rq * 4 + 2][cr] * sc;
        float t3 = tile[rq * 4 + 3][cr] * sc;
        uint2 o; o.x = pkbf(t0, t1); o.y = pkbf(t2, t3);
        *(uint2*)&dst[(size_t)(c0 + cr) * EMB + r0 + rq * 4] = o;
    }
}

// ---------------------------------------------------------------------------
// GEMM core (128x128): BK=32, depth-1 LDS double-buffer, xor swizzle
// s(row)=(row>>1)&3 (2-way on banks = free). Prefetch before MFMAs.
// ---------------------------------------------------------------------------
#define GEMM_STEP(B, KN)                                                                       \
    {                                                                                           \
        short8 a[4], b[4];                                                                      \
        _Pragma("unroll")                                                                       \
        for (int i = 0; i < 4; ++i) a[i] = *(const short8*)&As[B][wm * 64 + i * 16 + l15][ca];  \
        _Pragma("unroll")                                                                       \
        for (int j = 0; j < 4; ++j) b[j] = *(const short8*)&Bs[B][wn * 64 + j * 16 + l15][ca];  \
        if ((KN) < EMB) {                                                                       \
            for (int wl = wid; wl < 8; wl += 4) {                                               \
                async_copy16(&Ag[(size_t)(m0 + wl * 16 + rr) * EMB + (KN) + cc], &As[B ^ 1][wl * 16][0]); \
                async_copy16(&Bg[(size_t)(n0 + wl * 16 + rr) * EMB + (KN) + cc], &Bs[B ^ 1][wl * 16][0]); \
            }                                                                                   \
        }                                                                                       \
        _Pragma("unroll")                                                                       \
        for (int i = 0; i < 4; ++i)                                                             \
            _Pragma("unroll")                                                                   \
            for (int j = 0; j < 4; ++j)                                                         \
                acc[i][j] = MFMA16(a[i], b[j], acc[i][j]);                                      \
        __syncthreads();                                                                        \
    }

#define GEMM_CORE(A_, B_)                                                                      \
    const int tid = threadIdx.x;                                                                \
    const int lane = tid & 63, wid = tid >> 6;                                                  \
    const int wm = wid >> 1, wn = wid & 1;                                                      \
    const int l15 = lane & 15, lq = lane >> 4;                                                  \
    const int m0 = blockIdx.y * 128, n0 = blockIdx.x * 128;                                     \
    const u16* Ag = (A_);                                                                       \
    const u16* Bg = (B_);                                                                       \
    __shared__ u16 As[2][128][32];                                                              \
    __shared__ u16 Bs[2][128][32];                                                              \
    float4v acc[4][4] = {};                                                                     \
    const int rr = lane >> 2;                                                                   \
    const int cc = ((lane & 3) ^ ((rr >> 1) & 3)) * 8;                                          \
    const int ca = (lq ^ ((l15 >> 1) & 3)) * 8;                                                 \
    for (int wl = wid; wl < 8; wl += 4) {                                                       \
        async_copy16(&Ag[(size_t)(m0 + wl * 16 + rr) * EMB + cc], &As[0][wl * 16][0]);          \
        async_copy16(&Bg[(size_t)(n0 + wl * 16 + rr) * EMB + cc], &Bs[0][wl * 16][0]);          \
    }                                                                                           \
    __syncthreads();                                                                            \
    for (int k0 = 0; k0 < EMB; k0 += 64) {                                                      \
        GEMM_STEP(0, k0 + 32)                                                                   \
        GEMM_STEP(1, k0 + 64)                                                                   \
    }

// K2: fused 3-projection GEMM: z=0 Q[B,H,S,D], z=1 K[B,H,S,D], z=2 V^T[B,H,D,S]
__global__ __launch_bounds__(256) void gemm_proj_kernel(
    const u16* __restrict__ A, const u16* __restrict__ WtAll,
    u16* __restrict__ Qb, u16* __restrict__ Kb, u16* __restrict__ Vtb) {
    const int z = blockIdx.z;
    const u16* Wt = WtAll + (size_t)z * EMB * EMB;
    GEMM_CORE(A, Wt)
#pragma unroll
    for (int i = 0; i < 4; ++i)
#pragma unroll
        for (int j = 0; j < 4; ++j) {
            int mb = m0 + wm * 64 + i * 16 + lq * 4;      // 4 consecutive m
            int n  = n0 + wn * 64 + j * 16 + l15;
            int b_ = mb >> 11, s = mb & 2047;
            int h = n >> 6, d = n & 63;
            if (z == 2) {
                uint2 pv;
                pv.x = pkbf(acc[i][j][0], acc[i][j][1]);
                pv.y = pkbf(acc[i][j][2], acc[i][j][3]);
                *(uint2*)&Vtb[(((size_t)(b_ * NH + h) * HD + d) * S_LEN) + s] = pv;
            } else {
                u16* dst = (z == 1) ? Kb : Qb;
#pragma unroll
                for (int r = 0; r < 4; ++r)
                    dst[(((size_t)(b_ * NH + h) * S_LEN + s + r) * HD) + d] = f2bf(acc[i][j][r]);
            }
        }
}

// ---------------------------------------------------------------------------
// K4: output GEMM -> fp32. 128m x 64n tiles: grid (16,32) = 512 blocks.
// ---------------------------------------------------------------------------
__global__ __launch_bounds__(256) void gemm_out_kernel(
    const u16* __restrict__ A, const u16* __restrict__ Wt, float* __restrict__ out) {
    const int tid = threadIdx.x;
    const int lane = tid & 63, wid = tid >> 6;
    const int wm = wid >> 1, wn = wid & 1;
    const int l15 = lane & 15, lq = lane >> 4;
    const int m0 = blockIdx.y * 128, n0 = blockIdx.x * 64;
    __shared__ u16 As[2][128][32];
    __shared__ u16 Bs[2][64][32];
    float4v acc[4][2] = {};
    const int rr = lane >> 2;
    const int cc = ((lane & 3) ^ ((rr >> 1) & 3)) * 8;
    const int ca = (lq ^ ((l15 >> 1) & 3)) * 8;

#define GO_STAGE(B, KN)                                                                        \
    {                                                                                           \
        for (int wl = wid; wl < 8; wl += 4)                                                     \
            async_copy16(&A[(size_t)(m0 + wl * 16 + rr) * EMB + (KN) + cc], &As[B][wl * 16][0]);\
        async_copy16(&Wt[(size_t)(n0 + wid * 16 + rr) * EMB + (KN) + cc], &Bs[B][wid * 16][0]); \
    }
#define GO_STEP(B, KN)                                                                         \
    {                                                                                           \
        short8 a[4], b[2];                                                                      \
        _Pragma("unroll")                                                                       \
        for (int i = 0; i < 4; ++i) a[i] = *(const short8*)&As[B][wm * 64 + i * 16 + l15][ca];  \
        _Pragma("unroll")                                                                       \
        for (int j = 0; j < 2; ++j) b[j] = *(const short8*)&Bs[B][wn * 32 + j * 16 + l15][ca];  \
        if ((KN) < EMB) GO_STAGE(B ^ 1, KN)                                                     \
        _Pragma("unroll")                                                                       \
        for (int i = 0; i < 4; ++i)                                                             \
            _Pragma("unroll")                                                                   \
            for (int j = 0; j < 2; ++j)                                                         \
                acc[i][j] = MFMA16(a[i], b[j], acc[i][j]);                                      \
        __syncthreads();                                                                        \
    }

    GO_STAGE(0, 0)
    __syncthreads();
    for (int k0 = 0; k0 < EMB; k0 += 64) {
        GO_STEP(0, k0 + 32)
        GO_STEP(1, k0 + 64)
    }
#pragma unroll
    for (int i = 0; i < 4; ++i)
#pragma unroll
        for (int j = 0; j < 2; ++j)
#pragma unroll
            for (int r = 0; r < 4; ++r) {
                int m = m0 + wm * 64 + i * 16 + lq * 4 + r;
                int n = n0 + wn * 32 + j * 16 + l15;
                out[(size_t)m * EMB + n] = acc[i][j][r];
            }
}

// ---------------------------------------------------------------------------
// K3: flash attention (causal), S^T = K*Q^T, fixed-shift softmax (m=0).
// R10 = R1 data path + T4 COUNTED-VMCNT pipeline (the one verified mechanism
// never applied here). K/V 4-deep; stage tile t+2 during tile t; barrier is
// raw s_barrier preceded by s_waitcnt vmcnt(4) (tile t+1's 4 loads drained,
// tile t+2's 4 stay IN FLIGHT across the barrier — never vmcnt(0) in-loop).
// Slot safety: read slot = t&3, landing slot = (t+1)&3, issuing slot =
// (t+2)&3 — all distinct mod 4; overwritten slot last read at t-2 (2
// barriers ago); 1 barrier/tile keeps waves within one tile of lockstep.
// Ps is per-wave (no cross-wave hazard). Arithmetic order unchanged.
// LDS = Ks[4]+Vs[4]+Ps = 80 KiB -> 2 blocks/CU exactly (grid 512 = 2/CU).
// ---------------------------------------------------------------------------
#define ATTN_STAGE(SLOT, T)                                                                    \
    {                                                                                           \
        int kv0s = (T) * 64;                                                                    \
        u16 (*KsD)[64] = Ks[SLOT];                                                              \
        u16 (*VsD)[64] = Vs[SLOT];                                                              \
        for (int wl = wid; wl < 8; wl += 4) {                                                   \
            async_copy16(&Kb[(size_t)(kv0s + wl * 8 + rr8) * HD + cc8], &KsD[wl * 8][0]);       \
            async_copy16(&Vb[(size_t)(wl * 8 + rr8) * S_LEN + kv0s + cc8], &VsD[wl * 8][0]);    \
        }                                                                                       \
    }

// QK + mask + exp2 + pack + swizzled Ps write (no drain, no PV)
#define ATTN_QKSM(KF, T, QF, PS, QW)                                                           \
    {                                                                                           \
        const int kv0 = (T) * 64;                                                               \
        float4v sc[4];                                                                          \
        _Pragma("unroll")                                                                       \
        for (int nt = 0; nt < 4; ++nt) {                                                        \
            float4v c4 = {};                                                                    \
            c4 = MFMA16(KF[nt][0], QF[0], c4);                                                  \
            c4 = MFMA16(KF[nt][1], QF[1], c4);                                                  \
            sc[nt] = c4;                                                                        \
        }                                                                                       \
        if (kv0 + 63 > (QW)) {                                                                  \
            const int qi = (QW) + l15;                                                          \
            _Pragma("unroll")                                                                   \
            for (int nt = 0; nt < 4; ++nt)                                                      \
                _Pragma("unroll")                                                               \
                for (int r = 0; r < 4; ++r)                                                     \
                    if (kv0 + nt * 16 + lq * 4 + r > qi) sc[nt][r] = -__builtin_inff();         \
        }                                                                                       \
        _Pragma("unroll")                                                                       \
        for (int nt = 0; nt < 4; ++nt) {                                                        \
            float p0 = EXP2(sc[nt][0]);                                                         \
            float p1 = EXP2(sc[nt][1]);                                                         \
            float p2 = EXP2(sc[nt][2]);                                                         \
            float p3 = EXP2(sc[nt][3]);                                                         \
            uint2 pk;                                                                           \
            pk.x = pkbf(p0, p1);                                                                \
            pk.y = pkbf(p2, p3);                                                                \
            *(uint2*)((char*)&PS[l15][0] +                                                      \
                      (((nt * 2 + (lq >> 1)) ^ swp) * 16 + (lq & 1) * 8)) = pk;                 \
        }                                                                                       \
    }

#define ATTN_PV(PS, VF, OO, LS)                                                                \
    {                                                                                           \
        _Pragma("unroll")                                                                       \
        for (int kk = 0; kk < 2; ++kk) {                                                        \
            short8 pf = *(const short8*)((const char*)&PS[l15][0] +                             \
                                         (((kk * 4 + lq) ^ swp) * 16));                         \
            _Pragma("unroll")                                                                   \
            for (int nd = 0; nd < 4; ++nd)                                                      \
                OO[nd] = MFMA16(pf, VF[kk][nd], OO[nd]);                                        \
            LS = MFMA16(pf, ones8, LS);                                                         \
        }                                                                                       \
    }

#define ATTN_EPI(OO, LS, Q0)                                                                   \
    {                                                                                           \
        _Pragma("unroll")                                                                       \
        for (int r = 0; r < 4; ++r) {                                                           \
            float lr = 1.f / LS[r];                                                             \
            int s = (Q0) + wid * 16 + lq * 4 + r;                                               \
            size_t base = ((size_t)b * S_LEN + s) * EMB + h * HD;                               \
            _Pragma("unroll")                                                                   \
            for (int nd = 0; nd < 4; ++nd)                                                      \
                ctx[base + nd * 16 + l15] = f2bf(OO[nd][r] * lr);                               \
        }                                                                                       \
    }

__global__ __launch_bounds__(256, 2) void attn_kernel(
    const u16* __restrict__ Q, const u16* __restrict__ K,
    const u16* __restrict__ Vt, u16* __restrict__ ctx) {
    const int tid = threadIdx.x;
    const int lane = tid & 63, wid = tid >> 6;
    const int l15 = lane & 15, lq = lane >> 4;
    const int bh = blockIdx.x;               // x fastest: same-bh blocks same XCD
    const int b = bh >> 4, h = bh & 15;
    const int y = blockIdx.y;                // 0..15
    const int qa = y, qh = 31 - y;           // paired q-tiles: 33 units/block
    const int q0h = qh * 64, q0a = qa * 64;
    const int qwh = q0h + wid * 16, qwa = q0a + wid * 16;

    const u16* Qb = Q + (size_t)bh * S_LEN * HD;
    const u16* Kb = K + (size_t)bh * S_LEN * HD;
    const u16* Vb = Vt + (size_t)bh * HD * S_LEN;

    __shared__ u16 Ks[4][64][64];      // [kv][d], 4-deep, xor-swizzled (32 KB)
    __shared__ u16 Vs[4][64][64];      // [d][kv], 4-deep, xor-swizzled (32 KB)
    __shared__ u16 Ps[4][2][16][64];   // per-wave, per-set P (16 KB)
    // total LDS = 81920 B -> 2 blocks/CU exactly (grid 512 = 2/CU)

    u16 (*PsH)[64] = Ps[wid][0];
    u16 (*PsA)[64] = Ps[wid][1];

    const int rr8 = lane >> 3;
    const int cc8 = ((lane & 7) ^ rr8) * 8;  // s(row)=row&7
    const int swp = l15 & 7;                 // Ps chunk swizzle key

    // ones column for MFMA row-sum (bf16 1.0 = 0x3F80)
    short8 ones8;
#pragma unroll
    for (int i = 0; i < 8; ++i) ones8[i] = (short)0x3F80;

    // Q fragments for both q-sets (B-operand layout: lane n=l15 q-row, k=lq*8+j)
    short8 qfh[2], qfa[2];
#pragma unroll
    for (int ks = 0; ks < 2; ++ks) {
        qfh[ks] = *(const short8*)&Qb[(size_t)(qwh + l15) * HD + ks * 32 + lq * 8];
        qfa[ks] = *(const short8*)&Qb[(size_t)(qwa + l15) * HD + ks * 32 + lq * 8];
    }

    float4v Oh[4] = {}, Oa[4] = {};
    float4v lsh = {}, lsa = {};

    const int ntiles = qh + 1;               // 17..32
    // prologue: stage tiles 0 and 1; wait tile 0 landed (tile 1 in flight)
    ATTN_STAGE(0, 0)
    if (ntiles > 1) {
        ATTN_STAGE(1, 1)
        asm volatile("s_waitcnt vmcnt(4)" ::: "memory");
    } else {
        asm volatile("s_waitcnt vmcnt(0)" ::: "memory");
    }
    __builtin_amdgcn_s_barrier();

    for (int t = 0; t < ntiles; ++t) {
        const int slot = t & 3;
        if (t + 2 < ntiles) ATTN_STAGE((t + 2) & 3, t + 2)
        const u16 (*KsS)[64] = Ks[slot];
        const u16 (*VsS)[64] = Vs[slot];
        short8 kf[4][2];
#pragma unroll
        for (int nt = 0; nt < 4; ++nt) {
            int r_ = nt * 16 + l15;
            int sw = r_ & 7;
            kf[nt][0] = *(const short8*)&KsS[r_][(lq ^ sw) * 8];
            kf[nt][1] = *(const short8*)&KsS[r_][((lq + 4) ^ sw) * 8];
        }
        short8 vf[2][4];
#pragma unroll
        for (int kk = 0; kk < 2; ++kk)
#pragma unroll
            for (int nd = 0; nd < 4; ++nd) {
                int d = nd * 16 + l15;
                vf[kk][nd] = *(const short8*)&VsS[d][((kk * 4 + lq) ^ (d & 7)) * 8];
            }
        ATTN_QKSM(kf, t, qfh, PsH, qwh)
        if (t <= qa) ATTN_QKSM(kf, t, qfa, PsA, qwa)
        asm volatile("s_waitcnt lgkmcnt(0)" ::: "memory");
        ATTN_PV(PsH, vf, Oh, lsh)
        if (t <= qa) ATTN_PV(PsA, vf, Oa, lsa)
        // counted-vmcnt barrier: tile t+1's loads (oldest 4) drained, tile
        // t+2's 4 stay in flight across the barrier (T4 — never vmcnt(0)).
        if (t + 2 < ntiles) {
            asm volatile("s_waitcnt vmcnt(4) lgkmcnt(0)" ::: "memory");
        } else {
            asm volatile("s_waitcnt vmcnt(0) lgkmcnt(0)" ::: "memory");
        }
        __builtin_amdgcn_s_barrier();
    }

    ATTN_EPI(Oh, lsh, q0h)
    ATTN_EPI(Oa, lsa, q0a)
}

// ---------------------------------------------------------------------------
extern "C" void kernel_launch(void* const* d_in, const int* in_sizes, int n_in,
                              void* d_out, int out_size, void* d_ws, size_t ws_size,
                              hipStream_t stream) {
    const float* x  = (const float*)d_in[0];
    const float* wq = (const float*)d_in[1];
    const float* wk = (const float*)d_in[2];
    const float* wv = (const float*)d_in[3];
    const float* wo = (const float*)d_in[4];
    float* out = (float*)d_out;

    u16* ws  = (u16*)d_ws;
    u16* xb  = ws;                             // 4M : x bf16
    u16* Wt  = xb  + (size_t)4 * 1024 * 1024;  // 4M : 4 transposed weights
    u16* Qb  = Wt  + (size_t)4 * 1024 * 1024;  // 4M : Q [B,H,S,D] (pre-scaled)
    u16* Kb  = Qb  + (size_t)4 * 1024 * 1024;  // 4M : K [B,H,S,D]
    u16* Vtb = Kb  + (size_t)4 * 1024 * 1024;  // 4M : V^T [B,H,D,S]
    u16* ctx = Vtb + (size_t)4 * 1024 * 1024;  // 4M : ctx [B,S,E]

    prep_kernel<<<dim3(16, 16, 8), dim3(256), 0, stream>>>(x, wq, wk, wv, wo, xb, Wt);
    gemm_proj_kernel<<<dim3(8, 32, 3), dim3(256), 0, stream>>>(xb, Wt, Qb, Kb, Vtb);
    attn_kernel<<<dim3(32, 16), dim3(256), 0, stream>>>(Qb, Kb, Vtb, ctx);
    gemm_out_kernel<<<dim3(16, 32), dim3(256), 0, stream>>>(ctx, Wt + (size_t)3 * 1024 * 1024, out);
}